// Round 1
// baseline (680.555 us; speedup 1.0000x reference)
//
#include <hip/hip_runtime.h>

#define NPTS 1048576
#define NB 32
#define NBINS (NB * NB * NB)   // 32768

#define DHW0 (32 * 32 * 32)
#define DHW1 (64 * 64 * 64)
#define DHW2 (128 * 128 * 128)

typedef float v4f __attribute__((ext_vector_type(4)));

__device__ __forceinline__ void nt_store4(const float4& f, float4* p) {
    __builtin_nontemporal_store(*(const v4f*)&f, (v4f*)p);
}

// ---------------- math helpers ----------------

__device__ __forceinline__ float4 lerp4(const float4 a, const float4 b, const float t) {
    return make_float4(a.x + (b.x - a.x) * t,
                       a.y + (b.y - a.y) * t,
                       a.z + (b.z - a.z) * t,
                       a.w + (b.w - a.w) * t);
}

struct CoordW { float tx, ty, tz; int b00, b01, b10, b11, x0, x1; };

template<int D>
__device__ __forceinline__ CoordW mkcoord(float gx, float gy, float gz) {
    CoordW c;
    float x = fminf(fmaxf((gx + 1.0f) * (0.5f * (float)(D - 1)), 0.0f), (float)(D - 1));
    float y = fminf(fmaxf((gy + 1.0f) * (0.5f * (float)(D - 1)), 0.0f), (float)(D - 1));
    float z = fminf(fmaxf((gz + 1.0f) * (0.5f * (float)(D - 1)), 0.0f), (float)(D - 1));
    float xf = floorf(x), yf = floorf(y), zf = floorf(z);
    float tx = x - xf, ty = y - yf, tz = z - zf;
    c.tx = tx * tx * (3.0f - 2.0f * tx);
    c.ty = ty * ty * (3.0f - 2.0f * ty);
    c.tz = tz * tz * (3.0f - 2.0f * tz);
    int x0 = (int)xf, y0 = (int)yf, z0 = (int)zf;
    int y1 = min(y0 + 1, D - 1), z1 = min(z0 + 1, D - 1);
    c.x0 = x0;
    c.x1 = min(x0 + 1, D - 1);
    c.b00 = (z0 * D + y0) * D;
    c.b01 = (z0 * D + y1) * D;
    c.b10 = (z1 * D + y0) * D;
    c.b11 = (z1 * D + y1) * D;
    return c;
}

__device__ __forceinline__ float4 reduce8(const float4* q, const CoordW& c) {
    float4 c00 = lerp4(q[0], q[1], c.tx);
    float4 c01 = lerp4(q[2], q[3], c.tx);
    float4 c10 = lerp4(q[4], q[5], c.tx);
    float4 c11 = lerp4(q[6], q[7], c.tx);
    float4 c0 = lerp4(c00, c01, c.ty);
    float4 c1 = lerp4(c10, c11, c.ty);
    return lerp4(c0, c1, c.tz);
}

// ---------------- binning ----------------

__device__ __forceinline__ int bin_of(float gx, float gy, float gz) {
    float ux = fminf(fmaxf((gx + 1.0f) * 0.5f, 0.0f), 1.0f);
    float uy = fminf(fmaxf((gy + 1.0f) * 0.5f, 0.0f), 1.0f);
    float uz = fminf(fmaxf((gz + 1.0f) * 0.5f, 0.0f), 1.0f);
    int bx = min((int)(ux * (float)NB), NB - 1);
    int by = min((int)(uy * (float)NB), NB - 1);
    int bz = min((int)(uz * (float)NB), NB - 1);
    return (bz * NB + by) * NB + bx;
}

// ---------------- fused transpose [C,DHW]->[DHW,C] (3 vols) + histogram ----------------

__global__ __launch_bounds__(256) void xpose_hist_kernel(
    const float* __restrict__ v0, const float* __restrict__ v1, const float* __restrict__ v2,
    float4* __restrict__ w0, float4* __restrict__ w1, float4* __restrict__ w2,
    const float* __restrict__ grid, unsigned* __restrict__ hist)
{
    constexpr int B2 = DHW2 / 256, B1 = DHW1 / 256, B0 = DHW0 / 256;
    int b = blockIdx.x;
    int t = threadIdx.x;
    if (b < B2) {
        int v = b * 256 + t;
        w2[v] = make_float4(v2[v], v2[v + DHW2], v2[v + 2 * DHW2], v2[v + 3 * DHW2]);
    } else if (b < B2 + B1) {
        int v = (b - B2) * 256 + t;
        w1[v] = make_float4(v1[v], v1[v + DHW1], v1[v + 2 * DHW1], v1[v + 3 * DHW1]);
    } else if (b < B2 + B1 + B0) {
        int v = (b - B2 - B1) * 256 + t;
        w0[v] = make_float4(v0[v], v0[v + DHW0], v0[v + 2 * DHW0], v0[v + 3 * DHW0]);
    } else {
        int p = (b - B2 - B1 - B0) * 256 + t;
        float gx = grid[3 * p + 0];
        float gy = grid[3 * p + 1];
        float gz = grid[3 * p + 2];
        atomicAdd(&hist[bin_of(gx, gy, gz)], 1u);
    }
}

// single-workgroup exclusive scan of NBINS=32768 counts (1024 thr x 32 items)
__global__ __launch_bounds__(1024) void scan_kernel(const unsigned* __restrict__ hist,
                                                    unsigned* __restrict__ offsets) {
    __shared__ unsigned partial[1024];
    const int t = threadIdx.x;
    const int base = t * 32;
    unsigned sum = 0;
#pragma unroll
    for (int i = 0; i < 32; ++i) sum += hist[base + i];
    partial[t] = sum;
    __syncthreads();
    for (int off = 1; off < 1024; off <<= 1) {
        unsigned v = (t >= off) ? partial[t - off] : 0u;
        __syncthreads();
        partial[t] += v;
        __syncthreads();
    }
    unsigned run = partial[t] - sum;
#pragma unroll
    for (int i = 0; i < 32; ++i) {
        offsets[base + i] = run;
        run += hist[base + i];
    }
}

__global__ __launch_bounds__(256) void scatter_kernel(const float* __restrict__ grid,
                                                      unsigned* __restrict__ offsets,
                                                      float4* __restrict__ sorted,
                                                      int* __restrict__ inv) {
    int p = blockIdx.x * blockDim.x + threadIdx.x;
    float gx = grid[3 * p + 0];
    float gy = grid[3 * p + 1];
    float gz = grid[3 * p + 2];
    int b = bin_of(gx, gy, gz);
    unsigned pos = atomicAdd(&offsets[b], 1u);
    sorted[pos] = make_float4(gx, gy, gz, __int_as_float(p));
    inv[p] = (int)pos;
}

// ---------------- main gather over sorted points ----------------
// All 40 loads issued before ANY arithmetic, pinned by sched_barrier(0) so
// the register allocator cannot sink them back into small batches.
// Issue order == consume order (qa,qb,qc,qd), so FIFO vmcnt retirement lets
// f0..f2 proceed while the 16 v3 (HBM) loads are still in flight.
// launch_bounds(256,3): VGPR cap ~168, live set ~150 -> no spill, 3 waves/EU.

__global__ __launch_bounds__(256, 3) void gather_sorted_kernel(
    const float4* __restrict__ sorted,
    const float4* __restrict__ w0, const float4* __restrict__ w1,
    const float4* __restrict__ w2, const float* __restrict__ v3,
    float4* __restrict__ ws0, float4* __restrict__ ws1,
    float4* __restrict__ ws2, float4* __restrict__ ws3)
{
    // XCD swizzle: contiguous sorted range per XCD for L2 locality
    int bid = blockIdx.x;
    int sb = (bid & 7) * (int)(gridDim.x >> 3) + (bid >> 3);
    int s = sb * 256 + (int)threadIdx.x;
    float4 gp = sorted[s];
    float gx = gp.x, gy = gp.y, gz = gp.z;

    CoordW c0 = mkcoord<32>(gx, gy, gz);
    CoordW c1 = mkcoord<64>(gx, gy, gz);
    CoordW c2 = mkcoord<128>(gx, gy, gz);
    CoordW c3 = mkcoord<256>(gx, gy, gz);
    const int xm = min(c3.x0, 254);
    const bool edge = (c3.x0 == 255);

    // ---- issue ALL loads (w0, w1, w2 from L2-ish; v3 from HBM last) ----
    float4 qa[8], qb[8], qc[8];
    float2 qd[16];

    qa[0] = w0[c0.b00 + c0.x0]; qa[1] = w0[c0.b00 + c0.x1];
    qa[2] = w0[c0.b01 + c0.x0]; qa[3] = w0[c0.b01 + c0.x1];
    qa[4] = w0[c0.b10 + c0.x0]; qa[5] = w0[c0.b10 + c0.x1];
    qa[6] = w0[c0.b11 + c0.x0]; qa[7] = w0[c0.b11 + c0.x1];

    qb[0] = w1[c1.b00 + c1.x0]; qb[1] = w1[c1.b00 + c1.x1];
    qb[2] = w1[c1.b01 + c1.x0]; qb[3] = w1[c1.b01 + c1.x1];
    qb[4] = w1[c1.b10 + c1.x0]; qb[5] = w1[c1.b10 + c1.x1];
    qb[6] = w1[c1.b11 + c1.x0]; qb[7] = w1[c1.b11 + c1.x1];

    qc[0] = w2[c2.b00 + c2.x0]; qc[1] = w2[c2.b00 + c2.x1];
    qc[2] = w2[c2.b01 + c2.x0]; qc[3] = w2[c2.b01 + c2.x1];
    qc[4] = w2[c2.b10 + c2.x0]; qc[5] = w2[c2.b10 + c2.x1];
    qc[6] = w2[c2.b11 + c2.x0]; qc[7] = w2[c2.b11 + c2.x1];

#pragma unroll
    for (int ch = 0; ch < 4; ++ch) {
        const float* __restrict__ vc = v3 + (size_t)ch * (256 * 256 * 256);
        qd[ch * 4 + 0] = *(const float2*)(vc + c3.b00 + xm);
        qd[ch * 4 + 1] = *(const float2*)(vc + c3.b01 + xm);
        qd[ch * 4 + 2] = *(const float2*)(vc + c3.b10 + xm);
        qd[ch * 4 + 3] = *(const float2*)(vc + c3.b11 + xm);
    }

    // pin: no load may be sunk past this point, no use hoisted above it
    __builtin_amdgcn_sched_barrier(0);

    // ---- arithmetic (consume in issue order: vmcnt-friendly) ----
    float4 f0 = reduce8(qa, c0);
    nt_store4(f0, ws0 + s);
    float4 f1 = reduce8(qb, c1);
    nt_store4(f1, ws1 + s);
    float4 f2 = reduce8(qc, c2);
    nt_store4(f2, ws2 + s);

    float r3[4];
#pragma unroll
    for (int ch = 0; ch < 4; ++ch) {
        float v00a = edge ? qd[ch * 4 + 0].y : qd[ch * 4 + 0].x, v00b = qd[ch * 4 + 0].y;
        float v01a = edge ? qd[ch * 4 + 1].y : qd[ch * 4 + 1].x, v01b = qd[ch * 4 + 1].y;
        float v10a = edge ? qd[ch * 4 + 2].y : qd[ch * 4 + 2].x, v10b = qd[ch * 4 + 2].y;
        float v11a = edge ? qd[ch * 4 + 3].y : qd[ch * 4 + 3].x, v11b = qd[ch * 4 + 3].y;
        float c00 = v00a + (v00b - v00a) * c3.tx;
        float c01 = v01a + (v01b - v01a) * c3.tx;
        float c10 = v10a + (v10b - v10a) * c3.tx;
        float c11 = v11a + (v11b - v11a) * c3.tx;
        float e0 = c00 + (c01 - c00) * c3.ty;
        float e1 = c10 + (c11 - c10) * c3.ty;
        r3[ch] = e0 + (e1 - e0) * c3.tz;
    }
    float4 f3 = make_float4(r3[0], r3[1], r3[2], r3[3]);
    nt_store4(f3, ws3 + s);
}

// ---------------- inverse permute: SoA wsout -> [16][orig] ----------------
// Reads: 8 independent 16B gathers per thread (true MLP 8). Line-sharing with
// sorted-neighbor points is absorbed by the 256MB LLC (wsout = 64MB).
// Writes: 16 streams, 4B/lane, consecutive p across lanes -> full-line coalesced.

__device__ __forceinline__ void permute_one(const float4* __restrict__ ws0,
                                            const float4* __restrict__ ws1,
                                            const float4* __restrict__ ws2,
                                            const float4* __restrict__ ws3,
                                            int s, float* __restrict__ out, int p) {
    float4 f0 = ws0[s], f1 = ws1[s], f2 = ws2[s], f3 = ws3[s];
    __builtin_nontemporal_store(f0.x, &out[ 0 * NPTS + p]);
    __builtin_nontemporal_store(f0.y, &out[ 1 * NPTS + p]);
    __builtin_nontemporal_store(f0.z, &out[ 2 * NPTS + p]);
    __builtin_nontemporal_store(f0.w, &out[ 3 * NPTS + p]);
    __builtin_nontemporal_store(f1.x, &out[ 4 * NPTS + p]);
    __builtin_nontemporal_store(f1.y, &out[ 5 * NPTS + p]);
    __builtin_nontemporal_store(f1.z, &out[ 6 * NPTS + p]);
    __builtin_nontemporal_store(f1.w, &out[ 7 * NPTS + p]);
    __builtin_nontemporal_store(f2.x, &out[ 8 * NPTS + p]);
    __builtin_nontemporal_store(f2.y, &out[ 9 * NPTS + p]);
    __builtin_nontemporal_store(f2.z, &out[10 * NPTS + p]);
    __builtin_nontemporal_store(f2.w, &out[11 * NPTS + p]);
    __builtin_nontemporal_store(f3.x, &out[12 * NPTS + p]);
    __builtin_nontemporal_store(f3.y, &out[13 * NPTS + p]);
    __builtin_nontemporal_store(f3.z, &out[14 * NPTS + p]);
    __builtin_nontemporal_store(f3.w, &out[15 * NPTS + p]);
}

__global__ __launch_bounds__(256) void permute_kernel(
    const float4* __restrict__ ws0, const float4* __restrict__ ws1,
    const float4* __restrict__ ws2, const float4* __restrict__ ws3,
    const int* __restrict__ inv, float* __restrict__ out) {
    int p = blockIdx.x * blockDim.x + threadIdx.x;   // 0 .. NPTS/2-1
    int sA = inv[p];
    int sB = inv[p + NPTS / 2];
    // issue all 8 gathers before consuming
    float4 a0 = ws0[sA], a1 = ws1[sA], a2 = ws2[sA], a3 = ws3[sA];
    float4 b0 = ws0[sB], b1 = ws1[sB], b2 = ws2[sB], b3 = ws3[sB];
    __builtin_amdgcn_sched_barrier(0);
    {
        float4 f0 = a0, f1 = a1, f2 = a2, f3 = a3;
        int q = p;
        __builtin_nontemporal_store(f0.x, &out[ 0 * NPTS + q]);
        __builtin_nontemporal_store(f0.y, &out[ 1 * NPTS + q]);
        __builtin_nontemporal_store(f0.z, &out[ 2 * NPTS + q]);
        __builtin_nontemporal_store(f0.w, &out[ 3 * NPTS + q]);
        __builtin_nontemporal_store(f1.x, &out[ 4 * NPTS + q]);
        __builtin_nontemporal_store(f1.y, &out[ 5 * NPTS + q]);
        __builtin_nontemporal_store(f1.z, &out[ 6 * NPTS + q]);
        __builtin_nontemporal_store(f1.w, &out[ 7 * NPTS + q]);
        __builtin_nontemporal_store(f2.x, &out[ 8 * NPTS + q]);
        __builtin_nontemporal_store(f2.y, &out[ 9 * NPTS + q]);
        __builtin_nontemporal_store(f2.z, &out[10 * NPTS + q]);
        __builtin_nontemporal_store(f2.w, &out[11 * NPTS + q]);
        __builtin_nontemporal_store(f3.x, &out[12 * NPTS + q]);
        __builtin_nontemporal_store(f3.y, &out[13 * NPTS + q]);
        __builtin_nontemporal_store(f3.z, &out[14 * NPTS + q]);
        __builtin_nontemporal_store(f3.w, &out[15 * NPTS + q]);
    }
    {
        float4 f0 = b0, f1 = b1, f2 = b2, f3 = b3;
        int q = p + NPTS / 2;
        __builtin_nontemporal_store(f0.x, &out[ 0 * NPTS + q]);
        __builtin_nontemporal_store(f0.y, &out[ 1 * NPTS + q]);
        __builtin_nontemporal_store(f0.z, &out[ 2 * NPTS + q]);
        __builtin_nontemporal_store(f0.w, &out[ 3 * NPTS + q]);
        __builtin_nontemporal_store(f1.x, &out[ 4 * NPTS + q]);
        __builtin_nontemporal_store(f1.y, &out[ 5 * NPTS + q]);
        __builtin_nontemporal_store(f1.z, &out[ 6 * NPTS + q]);
        __builtin_nontemporal_store(f1.w, &out[ 7 * NPTS + q]);
        __builtin_nontemporal_store(f2.x, &out[ 8 * NPTS + q]);
        __builtin_nontemporal_store(f2.y, &out[ 9 * NPTS + q]);
        __builtin_nontemporal_store(f2.z, &out[10 * NPTS + q]);
        __builtin_nontemporal_store(f2.w, &out[11 * NPTS + q]);
        __builtin_nontemporal_store(f3.x, &out[12 * NPTS + q]);
        __builtin_nontemporal_store(f3.y, &out[13 * NPTS + q]);
        __builtin_nontemporal_store(f3.z, &out[14 * NPTS + q]);
        __builtin_nontemporal_store(f3.w, &out[15 * NPTS + q]);
    }
}

// ---------------- fallback paths ----------------

template<int D>
__device__ __forceinline__ float4 sample_inter(const float4* __restrict__ v,
                                               float gx, float gy, float gz) {
    CoordW c = mkcoord<D>(gx, gy, gz);
    float4 q[8];
    q[0] = v[c.b00 + c.x0]; q[1] = v[c.b00 + c.x1];
    q[2] = v[c.b01 + c.x0]; q[3] = v[c.b01 + c.x1];
    q[4] = v[c.b10 + c.x0]; q[5] = v[c.b10 + c.x1];
    q[6] = v[c.b11 + c.x0]; q[7] = v[c.b11 + c.x1];
    return reduce8(q, c);
}

template<int D>
__device__ __forceinline__ float4 sample_direct(const float* __restrict__ v,
                                                float gx, float gy, float gz) {
    CoordW c = mkcoord<D>(gx, gy, gz);
    float r[4];
#pragma unroll
    for (int ch = 0; ch < 4; ++ch) {
        const float* __restrict__ vc = v + (size_t)ch * (D * D * D);
        float c000 = vc[c.b00 + c.x0], c001 = vc[c.b00 + c.x1];
        float c010 = vc[c.b01 + c.x0], c011 = vc[c.b01 + c.x1];
        float c100 = vc[c.b10 + c.x0], c101 = vc[c.b10 + c.x1];
        float c110 = vc[c.b11 + c.x0], c111 = vc[c.b11 + c.x1];
        float c00 = c000 + (c001 - c000) * c.tx;
        float c01 = c010 + (c011 - c010) * c.tx;
        float c10 = c100 + (c101 - c100) * c.tx;
        float c11 = c110 + (c111 - c110) * c.tx;
        float e0 = c00 + (c01 - c00) * c.ty;
        float e1 = c10 + (c11 - c10) * c.ty;
        r[ch] = e0 + (e1 - e0) * c.tz;
    }
    return make_float4(r[0], r[1], r[2], r[3]);
}

__global__ __launch_bounds__(256) void mg_direct_kernel(
    const float* __restrict__ grid,
    const float* __restrict__ v0, const float* __restrict__ v1,
    const float* __restrict__ v2, const float* __restrict__ v3,
    float* __restrict__ out)
{
    int p = blockIdx.x * blockDim.x + threadIdx.x;
    float gx = grid[3 * p + 0];
    float gy = grid[3 * p + 1];
    float gz = grid[3 * p + 2];
    float4 f0 = sample_direct<32>(v0, gx, gy, gz);
    float4 f1 = sample_direct<64>(v1, gx, gy, gz);
    float4 f2 = sample_direct<128>(v2, gx, gy, gz);
    float4 f3 = sample_direct<256>(v3, gx, gy, gz);
    out[ 0 * NPTS + p] = f0.x; out[ 1 * NPTS + p] = f0.y;
    out[ 2 * NPTS + p] = f0.z; out[ 3 * NPTS + p] = f0.w;
    out[ 4 * NPTS + p] = f1.x; out[ 5 * NPTS + p] = f1.y;
    out[ 6 * NPTS + p] = f1.z; out[ 7 * NPTS + p] = f1.w;
    out[ 8 * NPTS + p] = f2.x; out[ 9 * NPTS + p] = f2.y;
    out[10 * NPTS + p] = f2.z; out[11 * NPTS + p] = f2.w;
    out[12 * NPTS + p] = f3.x; out[13 * NPTS + p] = f3.y;
    out[14 * NPTS + p] = f3.z; out[15 * NPTS + p] = f3.w;
}

__global__ __launch_bounds__(256) void mg_inter_kernel(
    const float* __restrict__ grid,
    const float4* __restrict__ w0, const float4* __restrict__ w1,
    const float4* __restrict__ w2, const float* __restrict__ v3,
    float* __restrict__ out)
{
    int p = blockIdx.x * blockDim.x + threadIdx.x;
    float gx = grid[3 * p + 0];
    float gy = grid[3 * p + 1];
    float gz = grid[3 * p + 2];
    float4 f0 = sample_inter<32>(w0, gx, gy, gz);
    float4 f1 = sample_inter<64>(w1, gx, gy, gz);
    float4 f2 = sample_inter<128>(w2, gx, gy, gz);
    float4 f3 = sample_direct<256>(v3, gx, gy, gz);
    out[ 0 * NPTS + p] = f0.x; out[ 1 * NPTS + p] = f0.y;
    out[ 2 * NPTS + p] = f0.z; out[ 3 * NPTS + p] = f0.w;
    out[ 4 * NPTS + p] = f1.x; out[ 5 * NPTS + p] = f1.y;
    out[ 6 * NPTS + p] = f1.z; out[ 7 * NPTS + p] = f1.w;
    out[ 8 * NPTS + p] = f2.x; out[ 9 * NPTS + p] = f2.y;
    out[10 * NPTS + p] = f2.z; out[11 * NPTS + p] = f2.w;
    out[12 * NPTS + p] = f3.x; out[13 * NPTS + p] = f3.y;
    out[14 * NPTS + p] = f3.z; out[15 * NPTS + p] = f3.w;
}

// ---------------- launch ----------------

extern "C" void kernel_launch(void* const* d_in, const int* in_sizes, int n_in,
                              void* d_out, int out_size, void* d_ws, size_t ws_size,
                              hipStream_t stream) {
    const float* grid = (const float*)d_in[0];
    const float* v0   = (const float*)d_in[1];   // [4,32,32,32]
    const float* v1   = (const float*)d_in[2];   // [4,64,64,64]
    const float* v2   = (const float*)d_in[3];   // [4,128,128,128]
    const float* v3   = (const float*)d_in[4];   // [4,256,256,256]
    float* out = (float*)d_out;

    // ws layout (bytes)
    constexpr size_t OFF_WSOUT  = 0;                                   // 64 MB (4 SoA float4 arrays)
    constexpr size_t OFF_SORTED = OFF_WSOUT  + (size_t)NPTS * 64;      // 16 MB
    constexpr size_t OFF_W2     = OFF_SORTED + (size_t)NPTS * 16;      // 32 MB
    constexpr size_t OFF_W1     = OFF_W2     + (size_t)DHW2 * 16;      // 4 MB
    constexpr size_t OFF_W0     = OFF_W1     + (size_t)DHW1 * 16;      // 0.5 MB
    constexpr size_t OFF_INV    = OFF_W0     + (size_t)DHW0 * 16;      // 4 MB
    constexpr size_t OFF_HIST   = OFF_INV    + (size_t)NPTS * 4;       // 128 KB
    constexpr size_t OFF_OFFS   = OFF_HIST   + (size_t)NBINS * 4;      // 128 KB
    constexpr size_t WS_FULL    = OFF_OFFS   + (size_t)NBINS * 4;      // ~120.8 MB
    constexpr size_t WS_INTER   = (size_t)(DHW0 + DHW1 + DHW2) * 16;   // 36.5 MB

    const int threads = 256;
    const int pt_blocks = NPTS / threads;   // 4096
    char* ws = (char*)d_ws;

    if (ws_size >= WS_FULL) {
        float4*   ws0    = (float4*)(ws + OFF_WSOUT);
        float4*   ws1    = ws0 + NPTS;
        float4*   ws2    = ws0 + 2 * (size_t)NPTS;
        float4*   ws3    = ws0 + 3 * (size_t)NPTS;
        float4*   sorted = (float4*)(ws + OFF_SORTED);
        float4*   w2     = (float4*)(ws + OFF_W2);
        float4*   w1     = (float4*)(ws + OFF_W1);
        float4*   w0     = (float4*)(ws + OFF_W0);
        int*      inv    = (int*)   (ws + OFF_INV);
        unsigned* hist   = (unsigned*)(ws + OFF_HIST);
        unsigned* offs   = (unsigned*)(ws + OFF_OFFS);

        (void)hipMemsetAsync(hist, 0, (size_t)NBINS * 4, stream);
        const int xh_blocks = (DHW0 + DHW1 + DHW2) / threads + pt_blocks;
        xpose_hist_kernel<<<xh_blocks, threads, 0, stream>>>(
            v0, v1, v2, w0, w1, w2, grid, hist);
        scan_kernel<<<1, 1024, 0, stream>>>(hist, offs);
        scatter_kernel<<<pt_blocks, threads, 0, stream>>>(grid, offs, sorted, inv);
        gather_sorted_kernel<<<pt_blocks, threads, 0, stream>>>(
            sorted, w0, w1, w2, v3, ws0, ws1, ws2, ws3);
        permute_kernel<<<pt_blocks / 2, threads, 0, stream>>>(ws0, ws1, ws2, ws3, inv, out);
    } else if (ws_size >= WS_INTER) {
        float4* w0 = (float4*)d_ws;
        float4* w1 = w0 + DHW0;
        float4* w2 = w1 + DHW1;
        xpose_hist_kernel<<<(DHW0 + DHW1 + DHW2) / threads, threads, 0, stream>>>(
            v0, v1, v2, w0, w1, w2, grid, (unsigned*)nullptr);
        mg_inter_kernel<<<pt_blocks, threads, 0, stream>>>(grid, w0, w1, w2, v3, out);
    } else {
        mg_direct_kernel<<<pt_blocks, threads, 0, stream>>>(grid, v0, v1, v2, v3, out);
    }
}

// Round 2
// 647.753 us; speedup vs baseline: 1.0506x; 1.0506x over previous
//
#include <hip/hip_runtime.h>

#define NPTS 1048576
#define NB 32
#define NBINS (NB * NB * NB)   // 32768

#define DHW0 (32 * 32 * 32)
#define DHW1 (64 * 64 * 64)
#define DHW2 (128 * 128 * 128)

typedef float v4f __attribute__((ext_vector_type(4)));

// ---------------- math helpers ----------------

__device__ __forceinline__ float4 lerp4(const float4 a, const float4 b, const float t) {
    return make_float4(a.x + (b.x - a.x) * t,
                       a.y + (b.y - a.y) * t,
                       a.z + (b.z - a.z) * t,
                       a.w + (b.w - a.w) * t);
}

struct CoordW { float tx, ty, tz; int b00, b01, b10, b11, x0, x1; };

template<int D>
__device__ __forceinline__ CoordW mkcoord(float gx, float gy, float gz) {
    CoordW c;
    float x = fminf(fmaxf((gx + 1.0f) * (0.5f * (float)(D - 1)), 0.0f), (float)(D - 1));
    float y = fminf(fmaxf((gy + 1.0f) * (0.5f * (float)(D - 1)), 0.0f), (float)(D - 1));
    float z = fminf(fmaxf((gz + 1.0f) * (0.5f * (float)(D - 1)), 0.0f), (float)(D - 1));
    float xf = floorf(x), yf = floorf(y), zf = floorf(z);
    float tx = x - xf, ty = y - yf, tz = z - zf;
    c.tx = tx * tx * (3.0f - 2.0f * tx);
    c.ty = ty * ty * (3.0f - 2.0f * ty);
    c.tz = tz * tz * (3.0f - 2.0f * tz);
    int x0 = (int)xf, y0 = (int)yf, z0 = (int)zf;
    int y1 = min(y0 + 1, D - 1), z1 = min(z0 + 1, D - 1);
    c.x0 = x0;
    c.x1 = min(x0 + 1, D - 1);
    c.b00 = (z0 * D + y0) * D;
    c.b01 = (z0 * D + y1) * D;
    c.b10 = (z1 * D + y0) * D;
    c.b11 = (z1 * D + y1) * D;
    return c;
}

__device__ __forceinline__ float4 reduce8(const float4* q, const CoordW& c) {
    float4 c00 = lerp4(q[0], q[1], c.tx);
    float4 c01 = lerp4(q[2], q[3], c.tx);
    float4 c10 = lerp4(q[4], q[5], c.tx);
    float4 c11 = lerp4(q[6], q[7], c.tx);
    float4 c0 = lerp4(c00, c01, c.ty);
    float4 c1 = lerp4(c10, c11, c.ty);
    return lerp4(c0, c1, c.tz);
}

// trilinear for the native-layout 256^3 volume from 16 float2 row-pairs
__device__ __forceinline__ float4 reduce_v3(const float2* qd, const CoordW& c, bool edge) {
    float r[4];
#pragma unroll
    for (int ch = 0; ch < 4; ++ch) {
        float v00a = edge ? qd[ch * 4 + 0].y : qd[ch * 4 + 0].x, v00b = qd[ch * 4 + 0].y;
        float v01a = edge ? qd[ch * 4 + 1].y : qd[ch * 4 + 1].x, v01b = qd[ch * 4 + 1].y;
        float v10a = edge ? qd[ch * 4 + 2].y : qd[ch * 4 + 2].x, v10b = qd[ch * 4 + 2].y;
        float v11a = edge ? qd[ch * 4 + 3].y : qd[ch * 4 + 3].x, v11b = qd[ch * 4 + 3].y;
        float c00 = v00a + (v00b - v00a) * c.tx;
        float c01 = v01a + (v01b - v01a) * c.tx;
        float c10 = v10a + (v10b - v10a) * c.tx;
        float c11 = v11a + (v11b - v11a) * c.tx;
        float e0 = c00 + (c01 - c00) * c.ty;
        float e1 = c10 + (c11 - c10) * c.ty;
        r[ch] = e0 + (e1 - e0) * c.tz;
    }
    return make_float4(r[0], r[1], r[2], r[3]);
}

// ---------------- binning ----------------

__device__ __forceinline__ int bin_of(float gx, float gy, float gz) {
    float ux = fminf(fmaxf((gx + 1.0f) * 0.5f, 0.0f), 1.0f);
    float uy = fminf(fmaxf((gy + 1.0f) * 0.5f, 0.0f), 1.0f);
    float uz = fminf(fmaxf((gz + 1.0f) * 0.5f, 0.0f), 1.0f);
    int bx = min((int)(ux * (float)NB), NB - 1);
    int by = min((int)(uy * (float)NB), NB - 1);
    int bz = min((int)(uz * (float)NB), NB - 1);
    return (bz * NB + by) * NB + bx;
}

// ---------------- fused transpose [C,DHW]->[DHW,C] (3 vols) + histogram ----------------

__global__ __launch_bounds__(256) void xpose_hist_kernel(
    const float* __restrict__ v0, const float* __restrict__ v1, const float* __restrict__ v2,
    float4* __restrict__ w0, float4* __restrict__ w1, float4* __restrict__ w2,
    const float* __restrict__ grid, unsigned* __restrict__ hist)
{
    constexpr int B2 = DHW2 / 256, B1 = DHW1 / 256, B0 = DHW0 / 256;
    int b = blockIdx.x;
    int t = threadIdx.x;
    if (b < B2) {
        int v = b * 256 + t;
        w2[v] = make_float4(v2[v], v2[v + DHW2], v2[v + 2 * DHW2], v2[v + 3 * DHW2]);
    } else if (b < B2 + B1) {
        int v = (b - B2) * 256 + t;
        w1[v] = make_float4(v1[v], v1[v + DHW1], v1[v + 2 * DHW1], v1[v + 3 * DHW1]);
    } else if (b < B2 + B1 + B0) {
        int v = (b - B2 - B1) * 256 + t;
        w0[v] = make_float4(v0[v], v0[v + DHW0], v0[v + 2 * DHW0], v0[v + 3 * DHW0]);
    } else {
        int p = (b - B2 - B1 - B0) * 256 + t;
        float gx = grid[3 * p + 0];
        float gy = grid[3 * p + 1];
        float gz = grid[3 * p + 2];
        atomicAdd(&hist[bin_of(gx, gy, gz)], 1u);
    }
}

// single-workgroup exclusive scan of NBINS=32768 counts (1024 thr x 32 items)
__global__ __launch_bounds__(1024) void scan_kernel(const unsigned* __restrict__ hist,
                                                    unsigned* __restrict__ offsets) {
    __shared__ unsigned partial[1024];
    const int t = threadIdx.x;
    const int base = t * 32;
    unsigned sum = 0;
#pragma unroll
    for (int i = 0; i < 32; ++i) sum += hist[base + i];
    partial[t] = sum;
    __syncthreads();
    for (int off = 1; off < 1024; off <<= 1) {
        unsigned v = (t >= off) ? partial[t - off] : 0u;
        __syncthreads();
        partial[t] += v;
        __syncthreads();
    }
    unsigned run = partial[t] - sum;
#pragma unroll
    for (int i = 0; i < 32; ++i) {
        offsets[base + i] = run;
        run += hist[base + i];
    }
}

__global__ __launch_bounds__(256) void scatter_kernel(const float* __restrict__ grid,
                                                      unsigned* __restrict__ offsets,
                                                      float4* __restrict__ sorted,
                                                      int* __restrict__ inv) {
    int p = blockIdx.x * blockDim.x + threadIdx.x;
    float gx = grid[3 * p + 0];
    float gy = grid[3 * p + 1];
    float gz = grid[3 * p + 2];
    int b = bin_of(gx, gy, gz);
    unsigned pos = atomicAdd(&offsets[b], 1u);
    sorted[pos] = make_float4(gx, gy, gz, __int_as_float(p));
    inv[p] = (int)pos;
}

// ---------------- main gather over sorted points ----------------
// 2 points per thread (s, s+256): B's loads overlap A's arithmetic (2-deep
// pipeline after the allocator batches). All loads issued before the
// sched_barrier; issue order == consume order (v3 last) so FIFO vmcnt lets
// f0..f2 math proceed while HBM (v3) loads are in flight.
// wsout is AoS [s][4] with CACHED stores: the four 16B quarter-line stores
// merge in L2 and write back as full 64B lines (NT stores here measured 1.8x
// write amplification in round 0; SoA fixed writes but cost permute 4x line
// touches on the read side in round 1).

__global__ __launch_bounds__(256, 3) void gather_sorted_kernel(
    const float4* __restrict__ sorted,
    const float4* __restrict__ w0, const float4* __restrict__ w1,
    const float4* __restrict__ w2, const float* __restrict__ v3,
    float4* __restrict__ wsout)
{
    // XCD swizzle: contiguous sorted range per XCD for L2 locality
    int bid = blockIdx.x;                                  // 2048 blocks
    int sb = (bid & 7) * (int)(gridDim.x >> 3) + (bid >> 3);
    int base = sb * 512 + (int)threadIdx.x;
    int sA = base, sB = base + 256;
    float4 gpA = sorted[sA];
    float4 gpB = sorted[sB];

    CoordW c0A = mkcoord<32>(gpA.x, gpA.y, gpA.z);
    CoordW c1A = mkcoord<64>(gpA.x, gpA.y, gpA.z);
    CoordW c2A = mkcoord<128>(gpA.x, gpA.y, gpA.z);
    CoordW c3A = mkcoord<256>(gpA.x, gpA.y, gpA.z);
    CoordW c0B = mkcoord<32>(gpB.x, gpB.y, gpB.z);
    CoordW c1B = mkcoord<64>(gpB.x, gpB.y, gpB.z);
    CoordW c2B = mkcoord<128>(gpB.x, gpB.y, gpB.z);
    CoordW c3B = mkcoord<256>(gpB.x, gpB.y, gpB.z);
    const int  xmA = min(c3A.x0, 254);
    const bool edgeA = (c3A.x0 == 255);
    const int  xmB = min(c3B.x0, 254);
    const bool edgeB = (c3B.x0 == 255);

    float4 qaA[8], qbA[8], qcA[8];
    float2 qdA[16];
    float4 qaB[8], qbB[8], qcB[8];
    float2 qdB[16];

    // ---- point A loads ----
    qaA[0] = w0[c0A.b00 + c0A.x0]; qaA[1] = w0[c0A.b00 + c0A.x1];
    qaA[2] = w0[c0A.b01 + c0A.x0]; qaA[3] = w0[c0A.b01 + c0A.x1];
    qaA[4] = w0[c0A.b10 + c0A.x0]; qaA[5] = w0[c0A.b10 + c0A.x1];
    qaA[6] = w0[c0A.b11 + c0A.x0]; qaA[7] = w0[c0A.b11 + c0A.x1];

    qbA[0] = w1[c1A.b00 + c1A.x0]; qbA[1] = w1[c1A.b00 + c1A.x1];
    qbA[2] = w1[c1A.b01 + c1A.x0]; qbA[3] = w1[c1A.b01 + c1A.x1];
    qbA[4] = w1[c1A.b10 + c1A.x0]; qbA[5] = w1[c1A.b10 + c1A.x1];
    qbA[6] = w1[c1A.b11 + c1A.x0]; qbA[7] = w1[c1A.b11 + c1A.x1];

    qcA[0] = w2[c2A.b00 + c2A.x0]; qcA[1] = w2[c2A.b00 + c2A.x1];
    qcA[2] = w2[c2A.b01 + c2A.x0]; qcA[3] = w2[c2A.b01 + c2A.x1];
    qcA[4] = w2[c2A.b10 + c2A.x0]; qcA[5] = w2[c2A.b10 + c2A.x1];
    qcA[6] = w2[c2A.b11 + c2A.x0]; qcA[7] = w2[c2A.b11 + c2A.x1];

#pragma unroll
    for (int ch = 0; ch < 4; ++ch) {
        const float* __restrict__ vc = v3 + (size_t)ch * (256 * 256 * 256);
        qdA[ch * 4 + 0] = *(const float2*)(vc + c3A.b00 + xmA);
        qdA[ch * 4 + 1] = *(const float2*)(vc + c3A.b01 + xmA);
        qdA[ch * 4 + 2] = *(const float2*)(vc + c3A.b10 + xmA);
        qdA[ch * 4 + 3] = *(const float2*)(vc + c3A.b11 + xmA);
    }

    // ---- point B loads ----
    qaB[0] = w0[c0B.b00 + c0B.x0]; qaB[1] = w0[c0B.b00 + c0B.x1];
    qaB[2] = w0[c0B.b01 + c0B.x0]; qaB[3] = w0[c0B.b01 + c0B.x1];
    qaB[4] = w0[c0B.b10 + c0B.x0]; qaB[5] = w0[c0B.b10 + c0B.x1];
    qaB[6] = w0[c0B.b11 + c0B.x0]; qaB[7] = w0[c0B.b11 + c0B.x1];

    qbB[0] = w1[c1B.b00 + c1B.x0]; qbB[1] = w1[c1B.b00 + c1B.x1];
    qbB[2] = w1[c1B.b01 + c1B.x0]; qbB[3] = w1[c1B.b01 + c1B.x1];
    qbB[4] = w1[c1B.b10 + c1B.x0]; qbB[5] = w1[c1B.b10 + c1B.x1];
    qbB[6] = w1[c1B.b11 + c1B.x0]; qbB[7] = w1[c1B.b11 + c1B.x1];

    qcB[0] = w2[c2B.b00 + c2B.x0]; qcB[1] = w2[c2B.b00 + c2B.x1];
    qcB[2] = w2[c2B.b01 + c2B.x0]; qcB[3] = w2[c2B.b01 + c2B.x1];
    qcB[4] = w2[c2B.b10 + c2B.x0]; qcB[5] = w2[c2B.b10 + c2B.x1];
    qcB[6] = w2[c2B.b11 + c2B.x0]; qcB[7] = w2[c2B.b11 + c2B.x1];

#pragma unroll
    for (int ch = 0; ch < 4; ++ch) {
        const float* __restrict__ vc = v3 + (size_t)ch * (256 * 256 * 256);
        qdB[ch * 4 + 0] = *(const float2*)(vc + c3B.b00 + xmB);
        qdB[ch * 4 + 1] = *(const float2*)(vc + c3B.b01 + xmB);
        qdB[ch * 4 + 2] = *(const float2*)(vc + c3B.b10 + xmB);
        qdB[ch * 4 + 3] = *(const float2*)(vc + c3B.b11 + xmB);
    }

    __builtin_amdgcn_sched_barrier(0);

    // ---- point A arithmetic + AoS cached stores ----
    float4* wA = wsout + (size_t)sA * 4;
    wA[0] = reduce8(qaA, c0A);
    wA[1] = reduce8(qbA, c1A);
    wA[2] = reduce8(qcA, c2A);
    wA[3] = reduce_v3(qdA, c3A, edgeA);

    // ---- point B arithmetic + AoS cached stores ----
    float4* wB = wsout + (size_t)sB * 4;
    wB[0] = reduce8(qaB, c0B);
    wB[1] = reduce8(qbB, c1B);
    wB[2] = reduce8(qcB, c2B);
    wB[3] = reduce_v3(qdB, c3B, edgeB);
}

// ---------------- inverse permute: AoS wsout -> [16][orig] ----------------
// 4 points per thread; all 16 AoS gathers (one 64B line per point) issued
// before any store (MLP 16). Writes: 64 NT 4B stores, consecutive p across
// lanes -> full-line coalesced.

__device__ __forceinline__ void store16(const float4 f0, const float4 f1,
                                        const float4 f2, const float4 f3,
                                        float* __restrict__ out, int p) {
    __builtin_nontemporal_store(f0.x, &out[ 0 * NPTS + p]);
    __builtin_nontemporal_store(f0.y, &out[ 1 * NPTS + p]);
    __builtin_nontemporal_store(f0.z, &out[ 2 * NPTS + p]);
    __builtin_nontemporal_store(f0.w, &out[ 3 * NPTS + p]);
    __builtin_nontemporal_store(f1.x, &out[ 4 * NPTS + p]);
    __builtin_nontemporal_store(f1.y, &out[ 5 * NPTS + p]);
    __builtin_nontemporal_store(f1.z, &out[ 6 * NPTS + p]);
    __builtin_nontemporal_store(f1.w, &out[ 7 * NPTS + p]);
    __builtin_nontemporal_store(f2.x, &out[ 8 * NPTS + p]);
    __builtin_nontemporal_store(f2.y, &out[ 9 * NPTS + p]);
    __builtin_nontemporal_store(f2.z, &out[10 * NPTS + p]);
    __builtin_nontemporal_store(f2.w, &out[11 * NPTS + p]);
    __builtin_nontemporal_store(f3.x, &out[12 * NPTS + p]);
    __builtin_nontemporal_store(f3.y, &out[13 * NPTS + p]);
    __builtin_nontemporal_store(f3.z, &out[14 * NPTS + p]);
    __builtin_nontemporal_store(f3.w, &out[15 * NPTS + p]);
}

__global__ __launch_bounds__(256) void permute_kernel(const float4* __restrict__ wsout,
                                                      const int* __restrict__ inv,
                                                      float* __restrict__ out) {
    int p = blockIdx.x * blockDim.x + threadIdx.x;   // 0 .. NPTS/4-1
    int pA = p, pB = p + NPTS / 4, pC = p + NPTS / 2, pD = p + 3 * (NPTS / 4);
    int sA = inv[pA], sB = inv[pB], sC = inv[pC], sD = inv[pD];
    const float4* wA = wsout + (size_t)sA * 4;
    const float4* wB = wsout + (size_t)sB * 4;
    const float4* wC = wsout + (size_t)sC * 4;
    const float4* wD = wsout + (size_t)sD * 4;
    float4 a0 = wA[0], a1 = wA[1], a2 = wA[2], a3 = wA[3];
    float4 b0 = wB[0], b1 = wB[1], b2 = wB[2], b3 = wB[3];
    float4 c0 = wC[0], c1 = wC[1], c2 = wC[2], c3 = wC[3];
    float4 d0 = wD[0], d1 = wD[1], d2 = wD[2], d3 = wD[3];
    __builtin_amdgcn_sched_barrier(0);
    store16(a0, a1, a2, a3, out, pA);
    store16(b0, b1, b2, b3, out, pB);
    store16(c0, c1, c2, c3, out, pC);
    store16(d0, d1, d2, d3, out, pD);
}

// ---------------- fallback paths ----------------

template<int D>
__device__ __forceinline__ float4 sample_inter(const float4* __restrict__ v,
                                               float gx, float gy, float gz) {
    CoordW c = mkcoord<D>(gx, gy, gz);
    float4 q[8];
    q[0] = v[c.b00 + c.x0]; q[1] = v[c.b00 + c.x1];
    q[2] = v[c.b01 + c.x0]; q[3] = v[c.b01 + c.x1];
    q[4] = v[c.b10 + c.x0]; q[5] = v[c.b10 + c.x1];
    q[6] = v[c.b11 + c.x0]; q[7] = v[c.b11 + c.x1];
    return reduce8(q, c);
}

template<int D>
__device__ __forceinline__ float4 sample_direct(const float* __restrict__ v,
                                                float gx, float gy, float gz) {
    CoordW c = mkcoord<D>(gx, gy, gz);
    float r[4];
#pragma unroll
    for (int ch = 0; ch < 4; ++ch) {
        const float* __restrict__ vc = v + (size_t)ch * (D * D * D);
        float c000 = vc[c.b00 + c.x0], c001 = vc[c.b00 + c.x1];
        float c010 = vc[c.b01 + c.x0], c011 = vc[c.b01 + c.x1];
        float c100 = vc[c.b10 + c.x0], c101 = vc[c.b10 + c.x1];
        float c110 = vc[c.b11 + c.x0], c111 = vc[c.b11 + c.x1];
        float c00 = c000 + (c001 - c000) * c.tx;
        float c01 = c010 + (c011 - c010) * c.tx;
        float c10 = c100 + (c101 - c100) * c.tx;
        float c11 = c110 + (c111 - c110) * c.tx;
        float e0 = c00 + (c01 - c00) * c.ty;
        float e1 = c10 + (c11 - c10) * c.ty;
        r[ch] = e0 + (e1 - e0) * c.tz;
    }
    return make_float4(r[0], r[1], r[2], r[3]);
}

__global__ __launch_bounds__(256) void mg_direct_kernel(
    const float* __restrict__ grid,
    const float* __restrict__ v0, const float* __restrict__ v1,
    const float* __restrict__ v2, const float* __restrict__ v3,
    float* __restrict__ out)
{
    int p = blockIdx.x * blockDim.x + threadIdx.x;
    float gx = grid[3 * p + 0];
    float gy = grid[3 * p + 1];
    float gz = grid[3 * p + 2];
    float4 f0 = sample_direct<32>(v0, gx, gy, gz);
    float4 f1 = sample_direct<64>(v1, gx, gy, gz);
    float4 f2 = sample_direct<128>(v2, gx, gy, gz);
    float4 f3 = sample_direct<256>(v3, gx, gy, gz);
    out[ 0 * NPTS + p] = f0.x; out[ 1 * NPTS + p] = f0.y;
    out[ 2 * NPTS + p] = f0.z; out[ 3 * NPTS + p] = f0.w;
    out[ 4 * NPTS + p] = f1.x; out[ 5 * NPTS + p] = f1.y;
    out[ 6 * NPTS + p] = f1.z; out[ 7 * NPTS + p] = f1.w;
    out[ 8 * NPTS + p] = f2.x; out[ 9 * NPTS + p] = f2.y;
    out[10 * NPTS + p] = f2.z; out[11 * NPTS + p] = f2.w;
    out[12 * NPTS + p] = f3.x; out[13 * NPTS + p] = f3.y;
    out[14 * NPTS + p] = f3.z; out[15 * NPTS + p] = f3.w;
}

__global__ __launch_bounds__(256) void mg_inter_kernel(
    const float* __restrict__ grid,
    const float4* __restrict__ w0, const float4* __restrict__ w1,
    const float4* __restrict__ w2, const float* __restrict__ v3,
    float* __restrict__ out)
{
    int p = blockIdx.x * blockDim.x + threadIdx.x;
    float gx = grid[3 * p + 0];
    float gy = grid[3 * p + 1];
    float gz = grid[3 * p + 2];
    float4 f0 = sample_inter<32>(w0, gx, gy, gz);
    float4 f1 = sample_inter<64>(w1, gx, gy, gz);
    float4 f2 = sample_inter<128>(w2, gx, gy, gz);
    float4 f3 = sample_direct<256>(v3, gx, gy, gz);
    out[ 0 * NPTS + p] = f0.x; out[ 1 * NPTS + p] = f0.y;
    out[ 2 * NPTS + p] = f0.z; out[ 3 * NPTS + p] = f0.w;
    out[ 4 * NPTS + p] = f1.x; out[ 5 * NPTS + p] = f1.y;
    out[ 6 * NPTS + p] = f1.z; out[ 7 * NPTS + p] = f1.w;
    out[ 8 * NPTS + p] = f2.x; out[ 9 * NPTS + p] = f2.y;
    out[10 * NPTS + p] = f2.z; out[11 * NPTS + p] = f2.w;
    out[12 * NPTS + p] = f3.x; out[13 * NPTS + p] = f3.y;
    out[14 * NPTS + p] = f3.z; out[15 * NPTS + p] = f3.w;
}

// ---------------- launch ----------------

extern "C" void kernel_launch(void* const* d_in, const int* in_sizes, int n_in,
                              void* d_out, int out_size, void* d_ws, size_t ws_size,
                              hipStream_t stream) {
    const float* grid = (const float*)d_in[0];
    const float* v0   = (const float*)d_in[1];   // [4,32,32,32]
    const float* v1   = (const float*)d_in[2];   // [4,64,64,64]
    const float* v2   = (const float*)d_in[3];   // [4,128,128,128]
    const float* v3   = (const float*)d_in[4];   // [4,256,256,256]
    float* out = (float*)d_out;

    // ws layout (bytes)
    constexpr size_t OFF_WSOUT  = 0;                                   // 64 MB (AoS [s][4])
    constexpr size_t OFF_SORTED = OFF_WSOUT  + (size_t)NPTS * 64;      // 16 MB
    constexpr size_t OFF_W2     = OFF_SORTED + (size_t)NPTS * 16;      // 32 MB
    constexpr size_t OFF_W1     = OFF_W2     + (size_t)DHW2 * 16;      // 4 MB
    constexpr size_t OFF_W0     = OFF_W1     + (size_t)DHW1 * 16;      // 0.5 MB
    constexpr size_t OFF_INV    = OFF_W0     + (size_t)DHW0 * 16;      // 4 MB
    constexpr size_t OFF_HIST   = OFF_INV    + (size_t)NPTS * 4;       // 128 KB
    constexpr size_t OFF_OFFS   = OFF_HIST   + (size_t)NBINS * 4;      // 128 KB
    constexpr size_t WS_FULL    = OFF_OFFS   + (size_t)NBINS * 4;      // ~120.8 MB
    constexpr size_t WS_INTER   = (size_t)(DHW0 + DHW1 + DHW2) * 16;   // 36.5 MB

    const int threads = 256;
    const int pt_blocks = NPTS / threads;   // 4096
    char* ws = (char*)d_ws;

    if (ws_size >= WS_FULL) {
        float4*   wsout  = (float4*)(ws + OFF_WSOUT);
        float4*   sorted = (float4*)(ws + OFF_SORTED);
        float4*   w2     = (float4*)(ws + OFF_W2);
        float4*   w1     = (float4*)(ws + OFF_W1);
        float4*   w0     = (float4*)(ws + OFF_W0);
        int*      inv    = (int*)   (ws + OFF_INV);
        unsigned* hist   = (unsigned*)(ws + OFF_HIST);
        unsigned* offs   = (unsigned*)(ws + OFF_OFFS);

        (void)hipMemsetAsync(hist, 0, (size_t)NBINS * 4, stream);
        const int xh_blocks = (DHW0 + DHW1 + DHW2) / threads + pt_blocks;
        xpose_hist_kernel<<<xh_blocks, threads, 0, stream>>>(
            v0, v1, v2, w0, w1, w2, grid, hist);
        scan_kernel<<<1, 1024, 0, stream>>>(hist, offs);
        scatter_kernel<<<pt_blocks, threads, 0, stream>>>(grid, offs, sorted, inv);
        gather_sorted_kernel<<<pt_blocks / 2, threads, 0, stream>>>(
            sorted, w0, w1, w2, v3, wsout);
        permute_kernel<<<pt_blocks / 4, threads, 0, stream>>>(wsout, inv, out);
    } else if (ws_size >= WS_INTER) {
        float4* w0 = (float4*)d_ws;
        float4* w1 = w0 + DHW0;
        float4* w2 = w1 + DHW1;
        xpose_hist_kernel<<<(DHW0 + DHW1 + DHW2) / threads, threads, 0, stream>>>(
            v0, v1, v2, w0, w1, w2, grid, (unsigned*)nullptr);
        mg_inter_kernel<<<pt_blocks, threads, 0, stream>>>(grid, w0, w1, w2, v3, out);
    } else {
        mg_direct_kernel<<<pt_blocks, threads, 0, stream>>>(grid, v0, v1, v2, v3, out);
    }
}